// Round 1
// baseline (687.669 us; speedup 1.0000x reference)
//
#include <hip/hip_runtime.h>
#include <hip/hip_bf16.h>
#include <math.h>

#define N_NODES 2000
#define DIN 256
#define DD 256
#define KTOP 10
#define CC 12
#define EG 64000
#define ET 50000
#define L1LEN 255
#define P1LEN 127
#define P2LEN 63
#define P3LEN 31
#define FLAT 2652
#define BN_INV 0.9999950000375f

// ---- workspace layout (float offsets). Total ~4.14 MB. ----
#define OFF_AGG    0
#define OFF_DEG    (OFF_AGG + N_NODES*DIN)      // 512000
#define OFF_H      (OFF_DEG + N_NODES)          // 514000
#define OFF_SC     (OFF_H + N_NODES*DD)         // 1026000
#define OFF_CONST1 (OFF_SC + N_NODES)           // 1028000
#define OFF_WA     (OFF_CONST1 + CC*L1LEN)      // 1031060  [t][o] 24
#define OFF_WB     (OFF_WA + 24)                // [t][o] 24
#define OFF_W2F    (OFF_WB + 24)                // [o][t][i] 288
#define OFF_B2F    (OFF_W2F + 288)              // 12
#define OFF_W3F    (OFF_B2F + 12)               // 288
#define OFF_B3F    (OFF_W3F + 288)              // 12
#define OFF_V      (OFF_B3F + 12)               // 2652
#define OFF_C0     (OFF_V + FLAT)               // 1

// ---------------- K1: scatter-add aggregation ----------------
__global__ void k_scatter(const float* __restrict__ x, const int* __restrict__ ei,
                          float* __restrict__ agg, float* __restrict__ deg) {
    int tid = blockIdx.x * 256 + threadIdx.x;
    int e = tid >> 6, c = tid & 63;
    if (e >= EG) return;
    int src = ei[e], dst = ei[EG + e];
    float4 v = *(const float4*)(x + src * DIN + c * 4);
    float* a = agg + dst * DIN + c * 4;
    atomicAdd(a + 0, v.x); atomicAdd(a + 1, v.y);
    atomicAdd(a + 2, v.z); atomicAdd(a + 3, v.w);
    if (c == 0) atomicAdd(deg + dst, 1.0f);
}

// ---------------- K2: h = relu(mean @ Wl^T + bl + x @ Wr^T) ----------------
// 32x32 tile, 256 threads (16x16), 2x2 microtile, k-tile 32.
__global__ void k_sage(const float* __restrict__ agg, const float* __restrict__ deg,
                       const float* __restrict__ x, const float* __restrict__ Wl,
                       const float* __restrict__ bl, const float* __restrict__ Wr,
                       float* __restrict__ h) {
    __shared__ float As[32][33], Xs[32][33], Bls[32][33], Brs[32][33];
    int tid = threadIdx.x;
    int tx = tid & 15, ty = tid >> 4;
    int n0 = blockIdx.y * 32, d0 = blockIdx.x * 32;
    int lrow = tid >> 3, lcol = (tid & 7) * 4;
    float acc[2][2] = {{0.f, 0.f}, {0.f, 0.f}};
    for (int k0 = 0; k0 < DIN; k0 += 32) {
        int gn = n0 + lrow;
        float4 av, xv;
        if (gn < N_NODES) {
            av = *(const float4*)(agg + gn * DIN + k0 + lcol);
            xv = *(const float4*)(x + gn * DIN + k0 + lcol);
            float rd = 1.0f / fmaxf(deg[gn], 1.0f);
            av.x *= rd; av.y *= rd; av.z *= rd; av.w *= rd;
        } else {
            av = make_float4(0.f, 0.f, 0.f, 0.f); xv = av;
        }
        As[lrow][lcol + 0] = av.x; As[lrow][lcol + 1] = av.y;
        As[lrow][lcol + 2] = av.z; As[lrow][lcol + 3] = av.w;
        Xs[lrow][lcol + 0] = xv.x; Xs[lrow][lcol + 1] = xv.y;
        Xs[lrow][lcol + 2] = xv.z; Xs[lrow][lcol + 3] = xv.w;
        int gd = d0 + lrow;  // always < 256
        float4 bv = *(const float4*)(Wl + gd * DIN + k0 + lcol);
        float4 rv = *(const float4*)(Wr + gd * DIN + k0 + lcol);
        Bls[lrow][lcol + 0] = bv.x; Bls[lrow][lcol + 1] = bv.y;
        Bls[lrow][lcol + 2] = bv.z; Bls[lrow][lcol + 3] = bv.w;
        Brs[lrow][lcol + 0] = rv.x; Brs[lrow][lcol + 1] = rv.y;
        Brs[lrow][lcol + 2] = rv.z; Brs[lrow][lcol + 3] = rv.w;
        __syncthreads();
#pragma unroll
        for (int kk = 0; kk < 32; ++kk) {
            float a0 = As[2 * ty][kk], a1 = As[2 * ty + 1][kk];
            float x0 = Xs[2 * ty][kk], x1 = Xs[2 * ty + 1][kk];
            float b0 = Bls[2 * tx][kk], b1 = Bls[2 * tx + 1][kk];
            float r0 = Brs[2 * tx][kk], r1 = Brs[2 * tx + 1][kk];
            acc[0][0] += a0 * b0 + x0 * r0; acc[0][1] += a0 * b1 + x0 * r1;
            acc[1][0] += a1 * b0 + x1 * r0; acc[1][1] += a1 * b1 + x1 * r1;
        }
        __syncthreads();
    }
#pragma unroll
    for (int i = 0; i < 2; ++i) {
        int n = n0 + 2 * ty + i;
        if (n < N_NODES) {
#pragma unroll
            for (int j = 0; j < 2; ++j) {
                int d = d0 + 2 * tx + j;
                h[n * DD + d] = fmaxf(acc[i][j] + bl[d], 0.0f);
            }
        }
    }
}

// ---------------- K3a: raw scores ----------------
__global__ void k_score(const float* __restrict__ h, const float* __restrict__ tw,
                        float* __restrict__ sc) {
    int wg = (blockIdx.x * 256 + threadIdx.x) >> 6;
    int lane = threadIdx.x & 63;
    if (wg >= N_NODES) return;
    const float* row = h + wg * DD;
    float s = 0.f;
    for (int k = lane; k < DD; k += 64) s += row[k] * tw[k];
#pragma unroll
    for (int off = 32; off > 0; off >>= 1) s += __shfl_xor(s, off, 64);
    if (lane == 0) sc[wg] = s;
}

// ---------------- K3b: top-k selection + const1 ----------------
__global__ void k_topk(const float* __restrict__ h, const float* __restrict__ tw,
                       const float* __restrict__ c1w, const float* __restrict__ c1b,
                       const float* __restrict__ bn1g, const float* __restrict__ bn1b,
                       float* __restrict__ W) {
    __shared__ float ls[N_NODES];
    __shared__ float rv[256];
    __shared__ int   ri[256];
    __shared__ float s_norm;
    __shared__ float s_tv[KTOP];
    __shared__ int   s_ti[KTOP];
    int tid = threadIdx.x;
    // ||tw||
    float p = 0.f;
    for (int k = tid; k < DD; k += 256) p += tw[k] * tw[k];
    rv[tid] = p; __syncthreads();
    for (int s = 128; s > 0; s >>= 1) { if (tid < s) rv[tid] += rv[tid + s]; __syncthreads(); }
    if (tid == 0) s_norm = sqrtf(rv[0]);
    const float* sc = W + OFF_SC;
    for (int i = tid; i < N_NODES; i += 256) ls[i] = sc[i];
    __syncthreads();
    for (int k = 0; k < KTOP; ++k) {
        float bv = -1e30f; int bi = 0x7fffffff;
        for (int i = tid; i < N_NODES; i += 256) {
            float v = ls[i];
            if (v > bv || (v == bv && i < bi)) { bv = v; bi = i; }
        }
        rv[tid] = bv; ri[tid] = bi; __syncthreads();
        for (int s = 128; s > 0; s >>= 1) {
            if (tid < s) {
                float ov = rv[tid + s]; int oi = ri[tid + s];
                if (ov > rv[tid] || (ov == rv[tid] && oi < ri[tid])) { rv[tid] = ov; ri[tid] = oi; }
            }
            __syncthreads();
        }
        if (tid == 0) { s_ti[k] = ri[0]; s_tv[k] = rv[0] / s_norm; ls[ri[0]] = -1e30f; }
        __syncthreads();
    }
    // const1[o][l]: fixed part of conv1 output (bias + bn biases + topk channels)
    float* c1c = W + OFF_CONST1;
    for (int j = tid; j < CC * L1LEN; j += 256) {
        int o = j / L1LEN, l = j - o * L1LEN;
        float sum = c1b[o];
        sum += (c1w[o * 24 + 0] + c1w[o * 24 + 1]) * bn1b[0];
        sum += (c1w[o * 24 + 2] + c1w[o * 24 + 3]) * bn1b[1];
#pragma unroll
        for (int r = 0; r < KTOP; ++r) {
            int ch = r + 2;
            float tv = tanhf(s_tv[r]);
            float sr = BN_INV * bn1g[ch];
            float br = bn1b[ch];
            const float* hr = h + s_ti[r] * DD;
            float v0 = hr[l] * tv * sr + br;
            float v1 = hr[l + 1] * tv * sr + br;
            sum += c1w[o * 24 + ch * 2] * v0 + c1w[o * 24 + ch * 2 + 1] * v1;
        }
        c1c[j] = sum;
    }
}

// ---------------- K3c: v = fc1_w^T (fc2_w * BN_INV * bn4_g) ----------------
__global__ void k_v(const float* __restrict__ fc1w, const float* __restrict__ fc2w,
                    const float* __restrict__ bn4g, float* __restrict__ W) {
    int j = blockIdx.x * 256 + threadIdx.x;
    if (j >= FLAT) return;
    float acc = 0.f;
    for (int k = 0; k < 128; ++k)
        acc += fc1w[k * FLAT + j] * (fc2w[k] * (BN_INV * bn4g[k]));
    W[OFF_V + j] = acc;
}

// ---------------- K3d: fold BN into conv weights; C0 ----------------
__global__ void k_fold(const float* __restrict__ c1w, const float* __restrict__ c2w,
                       const float* __restrict__ c2b, const float* __restrict__ c3w,
                       const float* __restrict__ c3b, const float* __restrict__ bn1g,
                       const float* __restrict__ bn2g, const float* __restrict__ bn2b,
                       const float* __restrict__ bn3g, const float* __restrict__ bn3b,
                       const float* __restrict__ bn4g, const float* __restrict__ bn4b,
                       const float* __restrict__ fc1b, const float* __restrict__ fc2w,
                       const float* __restrict__ fc2b, float* __restrict__ W) {
    int t = threadIdx.x;
    if (t < 288) {  // w2f/w3f layout [o][t][i]
        int o = t / 24, r = t - o * 24, tt = r / 12, i = r - tt * 12;
        W[OFF_W2F + t] = c2w[o * 24 + i * 2 + tt] * (BN_INV * bn2g[i]);
        W[OFF_W3F + t] = c3w[o * 24 + i * 2 + tt] * (BN_INV * bn3g[i]);
    }
    if (t < 12) {
        float s2 = c2b[t], s3 = c3b[t];
        for (int i = 0; i < 12; ++i) {
            s2 += (c2w[t * 24 + i * 2] + c2w[t * 24 + i * 2 + 1]) * bn2b[i];
            s3 += (c3w[t * 24 + i * 2] + c3w[t * 24 + i * 2 + 1]) * bn3b[i];
        }
        W[OFF_B2F + t] = s2;
        W[OFF_B3F + t] = s3;
    }
    if (t < 24) {  // wa/wb layout [t][o]
        int tt = t / 12, o = t - tt * 12;
        W[OFF_WA + t] = c1w[o * 24 + tt] * (BN_INV * bn1g[0]);
        W[OFF_WB + t] = c1w[o * 24 + 2 + tt] * (BN_INV * bn1g[1]);
    }
    if (t == 0) {
        float c = fc2b[0];
        for (int k = 0; k < 128; ++k)
            c += fc2w[k] * (fc1b[k] * (BN_INV * bn4g[k]) + bn4b[k]);
        W[OFF_C0] = c;
    }
}

// ---------------- K4: per-edge CNN pipeline + collapsed FC ----------------
// 1 wave per edge, 4 waves (edges) per block.
__launch_bounds__(256, 3)
__global__ void k_edges(const float* __restrict__ h, const int* __restrict__ te,
                        const float* __restrict__ W, float* __restrict__ out) {
    __shared__ float swt[648];
    __shared__ float sh[4][2][256];
    __shared__ float s1e[4][CC][64], s1o[4][CC][64];
    __shared__ float s2e[4][CC][32], s2o[4][CC][32];
    __shared__ float s3[4][CC][32];

    const int tid = threadIdx.x;
    const int w = tid >> 6, lane = tid & 63;
    const int e = blockIdx.x * 4 + w;

    for (int i = tid; i < 648; i += 256) swt[i] = W[OFF_WA + i];

    const int na = te[2 * e], nb = te[2 * e + 1];
    {
        float4 va = *(const float4*)(h + na * DD + lane * 4);
        float4 vb = *(const float4*)(h + nb * DD + lane * 4);
        *(float4*)(&sh[w][0][lane * 4]) = va;
        *(float4*)(&sh[w][1][lane * 4]) = vb;
    }
    __syncthreads();

    const float* swa = swt;        // [2][12]
    const float* swb = swt + 24;   // [2][12]
    const float* sw2 = swt + 48;   // [12][2][12]
    const float* sb2 = swt + 336;
    const float* sw3 = swt + 348;
    const float* sb3 = swt + 636;
    const float* c1c = W + OFF_CONST1;
    const float* vv  = W + OFF_V;

    // stage 1: conv1 (decomposed) + relu + pool -> s1[12][127] (even/odd split)
#pragma unroll
    for (int rep = 0; rep < 2; ++rep) {
        int p = lane + rep * 64;
        if (p < P1LEN) {
            float ha0 = sh[w][0][2 * p], ha1 = sh[w][0][2 * p + 1], ha2 = sh[w][0][2 * p + 2];
            float hb0 = sh[w][1][2 * p], hb1 = sh[w][1][2 * p + 1], hb2 = sh[w][1][2 * p + 2];
#pragma unroll
            for (int o = 0; o < CC; ++o) {
                float wa0 = swa[o], wa1 = swa[12 + o];
                float wb0 = swb[o], wb1 = swb[12 + o];
                float u0 = c1c[o * L1LEN + 2 * p]     + wa0 * ha0 + wa1 * ha1 + wb0 * hb0 + wb1 * hb1;
                float u1 = c1c[o * L1LEN + 2 * p + 1] + wa0 * ha1 + wa1 * ha2 + wb0 * hb1 + wb1 * hb2;
                float r = fmaxf(fmaxf(u0, u1), 0.0f);
                float* dst = (p & 1) ? &s1o[w][o][p >> 1] : &s1e[w][o][p >> 1];
                *dst = r;
            }
        }
    }
    __syncthreads();

    // stage 2: conv2 + relu + pool -> s2[12][63]
    if (lane < P2LEN) {
        int p = lane;
        float ve[CC], vo[CC], ve1[CC];
#pragma unroll
        for (int i = 0; i < CC; ++i) {
            ve[i] = s1e[w][i][p]; vo[i] = s1o[w][i][p]; ve1[i] = s1e[w][i][p + 1];
        }
#pragma unroll
        for (int o = 0; o < CC; ++o) {
            float a0 = sb2[o], a1 = sb2[o];
#pragma unroll
            for (int i = 0; i < CC; ++i) {
                float w0 = sw2[o * 24 + i], w1 = sw2[o * 24 + 12 + i];
                a0 += w0 * ve[i] + w1 * vo[i];
                a1 += w0 * vo[i] + w1 * ve1[i];
            }
            float r = fmaxf(fmaxf(a0, a1), 0.0f);
            float* dst = (p & 1) ? &s2o[w][o][p >> 1] : &s2e[w][o][p >> 1];
            *dst = r;
        }
    }
    __syncthreads();

    // stage 3: conv3 + relu + pool -> s3[12][31]; split o across half-waves
    {
        int grp = lane >> 5;
        int p = lane & 31;
        if (p < P3LEN) {
            float ve[CC], vo[CC], ve1[CC];
#pragma unroll
            for (int i = 0; i < CC; ++i) {
                ve[i] = s2e[w][i][p]; vo[i] = s2o[w][i][p]; ve1[i] = s2e[w][i][p + 1];
            }
#pragma unroll
            for (int oo = 0; oo < 6; ++oo) {
                int o = grp * 6 + oo;
                float a0 = sb3[o], a1 = sb3[o];
#pragma unroll
                for (int i = 0; i < CC; ++i) {
                    float w0 = sw3[o * 24 + i], w1 = sw3[o * 24 + 12 + i];
                    a0 += w0 * ve[i] + w1 * vo[i];
                    a1 += w0 * vo[i] + w1 * ve1[i];
                }
                s3[w][o][p] = fmaxf(fmaxf(a0, a1), 0.0f);
            }
        }
    }
    __syncthreads();

    // collapsed fc1->bn4->fc2: dot(z, v) + C0, then sigmoid
    float acc = 0.f;
#pragma unroll
    for (int c = 0; c < CC; ++c) {
        for (int pos = lane; pos < 221; pos += 64) {
            float z;
            if (pos < 127) {
                z = (pos & 1) ? s1o[w][c][pos >> 1] : s1e[w][c][pos >> 1];
            } else if (pos < 190) {
                int q = pos - 127;
                z = (q & 1) ? s2o[w][c][q >> 1] : s2e[w][c][q >> 1];
            } else {
                z = s3[w][c][pos - 190];
            }
            acc += z * vv[c * 221 + pos];
        }
    }
#pragma unroll
    for (int off = 32; off > 0; off >>= 1) acc += __shfl_xor(acc, off, 64);
    if (lane == 0) {
        float t = acc + W[OFF_C0];
        out[e] = 1.0f / (1.0f + expf(-t));
    }
}

extern "C" void kernel_launch(void* const* d_in, const int* in_sizes, int n_in,
                              void* d_out, int out_size, void* d_ws, size_t ws_size,
                              hipStream_t stream) {
    const float* x    = (const float*)d_in[0];
    const int*   ei   = (const int*)d_in[1];
    const int*   te   = (const int*)d_in[2];
    const float* Wl   = (const float*)d_in[3];
    const float* bl   = (const float*)d_in[4];
    const float* Wr   = (const float*)d_in[5];
    const float* tw   = (const float*)d_in[6];
    const float* c1w  = (const float*)d_in[7];
    const float* c1b  = (const float*)d_in[8];
    const float* c2w  = (const float*)d_in[9];
    const float* c2b  = (const float*)d_in[10];
    const float* c3w  = (const float*)d_in[11];
    const float* c3b  = (const float*)d_in[12];
    const float* bn1g = (const float*)d_in[13];
    const float* bn1b = (const float*)d_in[14];
    const float* bn2g = (const float*)d_in[15];
    const float* bn2b = (const float*)d_in[16];
    const float* bn3g = (const float*)d_in[17];
    const float* bn3b = (const float*)d_in[18];
    const float* bn4g = (const float*)d_in[19];
    const float* bn4b = (const float*)d_in[20];
    const float* fc1w = (const float*)d_in[21];
    const float* fc1b = (const float*)d_in[22];
    const float* fc2w = (const float*)d_in[23];
    const float* fc2b = (const float*)d_in[24];
    float* W   = (float*)d_ws;
    float* out = (float*)d_out;

    hipMemsetAsync(W + OFF_AGG, 0, (size_t)(N_NODES * DIN + N_NODES) * sizeof(float), stream);
    k_scatter<<<EG * 64 / 256, 256, 0, stream>>>(x, ei, W + OFF_AGG, W + OFF_DEG);
    dim3 g2(8, 63);
    k_sage<<<g2, 256, 0, stream>>>(W + OFF_AGG, W + OFF_DEG, x, Wl, bl, Wr, W + OFF_H);
    k_score<<<500, 256, 0, stream>>>(W + OFF_H, tw, W + OFF_SC);
    k_topk<<<1, 256, 0, stream>>>(W + OFF_H, tw, c1w, c1b, bn1g, bn1b, W);
    k_v<<<(FLAT + 255) / 256, 256, 0, stream>>>(fc1w, fc2w, bn4g, W);
    k_fold<<<1, 384, 0, stream>>>(c1w, c2w, c2b, c3w, c3b, bn1g, bn2g, bn2b, bn3g, bn3b,
                                  bn4g, bn4b, fc1b, fc2w, fc2b, W);
    k_edges<<<ET / 4, 256, 0, stream>>>(W + OFF_H, te, W, out);
}

// Round 2
// 223.454 us; speedup vs baseline: 3.0775x; 3.0775x over previous
//
#include <hip/hip_runtime.h>
#include <hip/hip_bf16.h>
#include <math.h>

#define N_NODES 2000
#define DIN 256
#define DD 256
#define KTOP 10
#define CC 12
#define EG 64000
#define ET 50000
#define L1LEN 255
#define P1LEN 127
#define P2LEN 63
#define P3LEN 31
#define FLAT 2652
#define BN_INV 0.9999950000375f

// ---- workspace layout (float offsets) ----
#define OFF_MEAN   0                         // 512000
#define OFF_H      512000                    // 512000
#define OFF_SC     1024000                   // 2000
#define OFF_CONST1 1026000                   // 12*256 = 3072 (padded stride 256)
#define OFF_WA     1029072                   // [t][o] 24
#define OFF_WB     1029096                   // 24
#define OFF_W2F    1029120                   // [o][t][i] 288
#define OFF_B2F    1029408                   // 12
#define OFF_W3F    1029420                   // 288
#define OFF_B3F    1029708                   // 12
#define OFF_V1     1029720                   // [12][128] = 1536
#define OFF_V2     1031256                   // [12][64]  = 768
#define OFF_V3     1032024                   // [12][32]  = 384
#define OFF_C0     1032408                   // 1
#define OFF_INT    1032412                   // int region: cnt[2000] offs[2000] cur[2000] nbr[64000]

// ---------------- CSR build ----------------
__global__ void k_count(const int* __restrict__ ei, int* __restrict__ I) {
    int e = blockIdx.x * 256 + threadIdx.x;
    if (e < EG) atomicAdd(&I[ei[EG + e]], 1);
}

__global__ void k_scan(int* __restrict__ I) {
    const int* cnt = I; int* offs = I + 2000; int* cur = I + 4000;
    __shared__ int part[256];
    int t = threadIdx.x;
    int base = t * 8, s = 0;
    int loc[8];
#pragma unroll
    for (int j = 0; j < 8; ++j) {
        int idx = base + j;
        int c = (idx < N_NODES) ? cnt[idx] : 0;
        loc[j] = c; s += c;
    }
    part[t] = s; __syncthreads();
    for (int d = 1; d < 256; d <<= 1) {
        int v = (t >= d) ? part[t - d] : 0;
        __syncthreads();
        part[t] += v;
        __syncthreads();
    }
    int run = part[t] - s;  // exclusive prefix
#pragma unroll
    for (int j = 0; j < 8; ++j) {
        int idx = base + j;
        if (idx < N_NODES) { offs[idx] = run; cur[idx] = run; run += loc[j]; }
    }
}

__global__ void k_fill(const int* __restrict__ ei, int* __restrict__ I) {
    int e = blockIdx.x * 256 + threadIdx.x;
    if (e >= EG) return;
    int dst = ei[EG + e], src = ei[e];
    int slot = atomicAdd(&I[4000 + dst], 1);
    I[6000 + slot] = src;
}

// one wave per node: mean over neighbors
__global__ void k_gather(const float* __restrict__ x, const int* __restrict__ I,
                         float* __restrict__ mean) {
    int w = threadIdx.x >> 6, lane = threadIdx.x & 63;
    int n = blockIdx.x * 4 + w;
    const int* cnt = I; const int* offs = I + 2000; const int* nbr = I + 6000;
    int dg = cnt[n], off = offs[n];
    float4 acc = make_float4(0.f, 0.f, 0.f, 0.f);
    int j = 0;
    for (; j + 4 <= dg; j += 4) {
        int s0 = nbr[off + j], s1 = nbr[off + j + 1], s2 = nbr[off + j + 2], s3 = nbr[off + j + 3];
        float4 v0 = *(const float4*)(x + s0 * DIN + lane * 4);
        float4 v1 = *(const float4*)(x + s1 * DIN + lane * 4);
        float4 v2 = *(const float4*)(x + s2 * DIN + lane * 4);
        float4 v3 = *(const float4*)(x + s3 * DIN + lane * 4);
        acc.x += v0.x + v1.x + v2.x + v3.x;
        acc.y += v0.y + v1.y + v2.y + v3.y;
        acc.z += v0.z + v1.z + v2.z + v3.z;
        acc.w += v0.w + v1.w + v2.w + v3.w;
    }
    for (; j < dg; ++j) {
        int s0 = nbr[off + j];
        float4 v0 = *(const float4*)(x + s0 * DIN + lane * 4);
        acc.x += v0.x; acc.y += v0.y; acc.z += v0.z; acc.w += v0.w;
    }
    float rd = 1.0f / fmaxf((float)dg, 1.0f);
    *(float4*)(mean + n * DIN + lane * 4) =
        make_float4(acc.x * rd, acc.y * rd, acc.z * rd, acc.w * rd);
}

// ---------------- h = relu(mean @ Wl^T + bl + x @ Wr^T) ----------------
__global__ void k_sage(const float* __restrict__ mean, const float* __restrict__ x,
                       const float* __restrict__ Wl, const float* __restrict__ bl,
                       const float* __restrict__ Wr, float* __restrict__ h) {
    __shared__ float As[32][33], Xs[32][33], Bls[32][33], Brs[32][33];
    int tid = threadIdx.x;
    int tx = tid & 15, ty = tid >> 4;
    int n0 = blockIdx.y * 32, d0 = blockIdx.x * 32;
    int lrow = tid >> 3, lcol = (tid & 7) * 4;
    float acc[2][2] = {{0.f, 0.f}, {0.f, 0.f}};
    for (int k0 = 0; k0 < DIN; k0 += 32) {
        int gn = n0 + lrow;
        float4 av, xv;
        if (gn < N_NODES) {
            av = *(const float4*)(mean + gn * DIN + k0 + lcol);
            xv = *(const float4*)(x + gn * DIN + k0 + lcol);
        } else {
            av = make_float4(0.f, 0.f, 0.f, 0.f); xv = av;
        }
        As[lrow][lcol + 0] = av.x; As[lrow][lcol + 1] = av.y;
        As[lrow][lcol + 2] = av.z; As[lrow][lcol + 3] = av.w;
        Xs[lrow][lcol + 0] = xv.x; Xs[lrow][lcol + 1] = xv.y;
        Xs[lrow][lcol + 2] = xv.z; Xs[lrow][lcol + 3] = xv.w;
        int gd = d0 + lrow;
        float4 bv = *(const float4*)(Wl + gd * DIN + k0 + lcol);
        float4 rv = *(const float4*)(Wr + gd * DIN + k0 + lcol);
        Bls[lrow][lcol + 0] = bv.x; Bls[lrow][lcol + 1] = bv.y;
        Bls[lrow][lcol + 2] = bv.z; Bls[lrow][lcol + 3] = bv.w;
        Brs[lrow][lcol + 0] = rv.x; Brs[lrow][lcol + 1] = rv.y;
        Brs[lrow][lcol + 2] = rv.z; Brs[lrow][lcol + 3] = rv.w;
        __syncthreads();
#pragma unroll
        for (int kk = 0; kk < 32; ++kk) {
            float a0 = As[2 * ty][kk], a1 = As[2 * ty + 1][kk];
            float x0 = Xs[2 * ty][kk], x1 = Xs[2 * ty + 1][kk];
            float b0 = Bls[2 * tx][kk], b1 = Bls[2 * tx + 1][kk];
            float r0 = Brs[2 * tx][kk], r1 = Brs[2 * tx + 1][kk];
            acc[0][0] += a0 * b0 + x0 * r0; acc[0][1] += a0 * b1 + x0 * r1;
            acc[1][0] += a1 * b0 + x1 * r0; acc[1][1] += a1 * b1 + x1 * r1;
        }
        __syncthreads();
    }
#pragma unroll
    for (int i = 0; i < 2; ++i) {
        int n = n0 + 2 * ty + i;
        if (n < N_NODES) {
#pragma unroll
            for (int j = 0; j < 2; ++j) {
                int d = d0 + 2 * tx + j;
                h[n * DD + d] = fmaxf(acc[i][j] + bl[d], 0.0f);
            }
        }
    }
}

// ---------------- raw scores ----------------
__global__ void k_score(const float* __restrict__ h, const float* __restrict__ tw,
                        float* __restrict__ sc) {
    int wg = (blockIdx.x * 256 + threadIdx.x) >> 6;
    int lane = threadIdx.x & 63;
    if (wg >= N_NODES) return;
    const float* row = h + wg * DD;
    float s = 0.f;
    for (int k = lane; k < DD; k += 64) s += row[k] * tw[k];
#pragma unroll
    for (int off = 32; off > 0; off >>= 1) s += __shfl_xor(s, off, 64);
    if (lane == 0) sc[wg] = s;
}

// ---------------- top-k selection + const1 ----------------
__global__ void k_topk(const float* __restrict__ h, const float* __restrict__ tw,
                       const float* __restrict__ c1w, const float* __restrict__ c1b,
                       const float* __restrict__ bn1g, const float* __restrict__ bn1b,
                       float* __restrict__ W) {
    __shared__ float ls[N_NODES];
    __shared__ float rv[256];
    __shared__ int   ri[256];
    __shared__ float s_norm;
    __shared__ float s_tv[KTOP];
    __shared__ int   s_ti[KTOP];
    int tid = threadIdx.x;
    float p = 0.f;
    for (int k = tid; k < DD; k += 256) p += tw[k] * tw[k];
    rv[tid] = p; __syncthreads();
    for (int s = 128; s > 0; s >>= 1) { if (tid < s) rv[tid] += rv[tid + s]; __syncthreads(); }
    if (tid == 0) s_norm = sqrtf(rv[0]);
    const float* sc = W + OFF_SC;
    for (int i = tid; i < N_NODES; i += 256) ls[i] = sc[i];
    __syncthreads();
    for (int k = 0; k < KTOP; ++k) {
        float bv = -1e30f; int bi = 0x7fffffff;
        for (int i = tid; i < N_NODES; i += 256) {
            float v = ls[i];
            if (v > bv || (v == bv && i < bi)) { bv = v; bi = i; }
        }
        rv[tid] = bv; ri[tid] = bi; __syncthreads();
        for (int s = 128; s > 0; s >>= 1) {
            if (tid < s) {
                float ov = rv[tid + s]; int oi = ri[tid + s];
                if (ov > rv[tid] || (ov == rv[tid] && oi < ri[tid])) { rv[tid] = ov; ri[tid] = oi; }
            }
            __syncthreads();
        }
        if (tid == 0) { s_ti[k] = ri[0]; s_tv[k] = rv[0] / s_norm; ls[ri[0]] = -1e30f; }
        __syncthreads();
    }
    float* c1c = W + OFF_CONST1;   // [12][256] padded
    for (int jj = tid; jj < CC * L1LEN; jj += 256) {
        int o = jj / L1LEN, l = jj - o * L1LEN;
        float sum = c1b[o];
        sum += (c1w[o * 24 + 0] + c1w[o * 24 + 1]) * bn1b[0];
        sum += (c1w[o * 24 + 2] + c1w[o * 24 + 3]) * bn1b[1];
#pragma unroll
        for (int r = 0; r < KTOP; ++r) {
            int ch = r + 2;
            float tv = tanhf(s_tv[r]);
            float sr = BN_INV * bn1g[ch];
            float br = bn1b[ch];
            const float* hr = h + s_ti[r] * DD;
            float v0 = hr[l] * tv * sr + br;
            float v1 = hr[l + 1] * tv * sr + br;
            sum += c1w[o * 24 + ch * 2] * v0 + c1w[o * 24 + ch * 2 + 1] * v1;
        }
        c1c[o * 256 + l] = sum;
    }
}

// ---------------- prep: v-split tables + folded weights + C0 ----------------
__global__ void k_prep(const float* __restrict__ fc1w, const float* __restrict__ fc2w,
                       const float* __restrict__ bn4g, const float* __restrict__ c1w,
                       const float* __restrict__ c2w, const float* __restrict__ c2b,
                       const float* __restrict__ c3w, const float* __restrict__ c3b,
                       const float* __restrict__ bn1g, const float* __restrict__ bn2g,
                       const float* __restrict__ bn2b, const float* __restrict__ bn3g,
                       const float* __restrict__ bn3b, const float* __restrict__ bn4b,
                       const float* __restrict__ fc1b, const float* __restrict__ fc2b,
                       float* __restrict__ W) {
    int tid = threadIdx.x;
    if (blockIdx.x < 11) {
        int j = blockIdx.x * 256 + tid;
        if (j >= FLAT) return;
        float acc = 0.f;
        for (int k = 0; k < 128; ++k)
            acc += fc1w[k * FLAT + j] * (fc2w[k] * (BN_INV * bn4g[k]));
        int c = j / 221, pos = j - c * 221;
        if (pos < 127)      W[OFF_V1 + c * 128 + pos] = acc;
        else if (pos < 190) W[OFF_V2 + c * 64 + (pos - 127)] = acc;
        else                W[OFF_V3 + c * 32 + (pos - 190)] = acc;
        return;
    }
    // fold block
    for (int t = tid; t < 288; t += 256) {
        int o = t / 24, r = t - o * 24, tt = r / 12, i = r - tt * 12;
        W[OFF_W2F + t] = c2w[o * 24 + i * 2 + tt] * (BN_INV * bn2g[i]);
        W[OFF_W3F + t] = c3w[o * 24 + i * 2 + tt] * (BN_INV * bn3g[i]);
    }
    if (tid < 12) {
        float s2 = c2b[tid], s3 = c3b[tid];
        for (int i = 0; i < 12; ++i) {
            s2 += (c2w[tid * 24 + i * 2] + c2w[tid * 24 + i * 2 + 1]) * bn2b[i];
            s3 += (c3w[tid * 24 + i * 2] + c3w[tid * 24 + i * 2 + 1]) * bn3b[i];
        }
        W[OFF_B2F + tid] = s2;
        W[OFF_B3F + tid] = s3;
    }
    if (tid < 24) {
        int tt = tid / 12, o = tid - tt * 12;
        W[OFF_WA + tid] = c1w[o * 24 + tt] * (BN_INV * bn1g[0]);
        W[OFF_WB + tid] = c1w[o * 24 + 2 + tt] * (BN_INV * bn1g[1]);
    }
    if (tid == 0) {
        float c = fc2b[0];
        for (int k = 0; k < 128; ++k)
            c += fc2w[k] * (fc1b[k] * (BN_INV * bn4g[k]) + bn4b[k]);
        W[OFF_C0] = c;
    }
}

// ---------------- per-edge CNN pipeline, dot fused at production ----------------
// 1 wave per edge, 4 waves per block, no __syncthreads (wave-private LDS slices).
__launch_bounds__(256, 4)
__global__ void k_edges(const float* __restrict__ h, const int* __restrict__ te,
                        const float* __restrict__ W, float* __restrict__ out) {
    __shared__ float s1[4][CC][128];
    __shared__ float s2[4][CC][64];
    const int tid = threadIdx.x;
    const int w = tid >> 6, lane = tid & 63;
    const int e = blockIdx.x * 4 + w;

    int na = __builtin_amdgcn_readfirstlane(te[2 * e]);
    int nb = __builtin_amdgcn_readfirstlane(te[2 * e + 1]);
    const float* ha = h + na * DD;
    const float* hb = h + nb * DD;
    const float* c1c = W + OFF_CONST1;
    const float* wa = W + OFF_WA;
    const float* wb = W + OFF_WB;
    const float* w2 = W + OFF_W2F;
    const float* b2 = W + OFF_B2F;
    const float* w3 = W + OFF_W3F;
    const float* b3 = W + OFF_B3F;
    const float* V1 = W + OFF_V1;
    const float* V2 = W + OFF_V2;
    const float* V3 = W + OFF_V3;

    float dot = 0.f;

    // ---- stage 1: conv1 (decomposed) + relu + pool ----
#pragma unroll
    for (int rep = 0; rep < 2; ++rep) {
        int p = lane + rep * 64;
        if (p < P1LEN) {
            float2 a01 = *(const float2*)(ha + 2 * p);
            float  a2  = ha[2 * p + 2];
            float2 b01 = *(const float2*)(hb + 2 * p);
            float  b2v = hb[2 * p + 2];
#pragma unroll
            for (int o = 0; o < CC; ++o) {
                float2 cc = *(const float2*)(c1c + o * 256 + 2 * p);
                float u0 = fmaf(wa[o], a01.x, cc.x);
                u0 = fmaf(wa[12 + o], a01.y, u0);
                u0 = fmaf(wb[o], b01.x, u0);
                u0 = fmaf(wb[12 + o], b01.y, u0);
                float u1 = fmaf(wa[o], a01.y, cc.y);
                u1 = fmaf(wa[12 + o], a2, u1);
                u1 = fmaf(wb[o], b01.y, u1);
                u1 = fmaf(wb[12 + o], b2v, u1);
                float r = fmaxf(fmaxf(u0, u1), 0.0f);
                s1[w][o][p] = r;
                dot = fmaf(r, V1[o * 128 + p], dot);
            }
        }
    }
    __builtin_amdgcn_wave_barrier();

    // ---- stage 2: conv2 + relu + pool ----
    if (lane < P2LEN) {
        int p = lane;
        float ve[CC], vo[CC], v1e[CC];
#pragma unroll
        for (int i = 0; i < CC; ++i) {
            float2 t2 = *(const float2*)(&s1[w][i][2 * p]);
            ve[i] = t2.x; vo[i] = t2.y; v1e[i] = s1[w][i][2 * p + 2];
        }
#pragma unroll
        for (int o = 0; o < CC; ++o) {
            float a0 = b2[o], a1 = b2[o];
#pragma unroll
            for (int i = 0; i < CC; ++i) {
                float w0 = w2[o * 24 + i], w1 = w2[o * 24 + 12 + i];
                a0 = fmaf(w0, ve[i], a0); a0 = fmaf(w1, vo[i], a0);
                a1 = fmaf(w0, vo[i], a1); a1 = fmaf(w1, v1e[i], a1);
            }
            float r = fmaxf(fmaxf(a0, a1), 0.0f);
            s2[w][o][p] = r;
            dot = fmaf(r, V2[o * 64 + p], dot);
        }
    }
    __builtin_amdgcn_wave_barrier();

    // ---- stage 3: conv3 position-per-lane + shfl pooling, fused dot ----
    {
        int q = (lane < 62) ? lane : 61;   // conv position (pre-pool), clamp for safety
        float ve[CC], vq1[CC];
#pragma unroll
        for (int i = 0; i < CC; ++i) {
            ve[i] = s2[w][i][q];
            vq1[i] = s2[w][i][q + 1];
        }
        bool take = ((lane & 1) == 0) && (lane < 62);
        int t = lane >> 1;
#pragma unroll
        for (int o = 0; o < CC; ++o) {
            float a = b3[o];
#pragma unroll
            for (int i = 0; i < CC; ++i) {
                a = fmaf(w3[o * 24 + i], ve[i], a);
                a = fmaf(w3[o * 24 + 12 + i], vq1[i], a);
            }
            float partner = __shfl_xor(a, 1, 64);
            float r = fmaxf(fmaxf(a, partner), 0.0f);
            if (take) dot = fmaf(r, V3[o * 32 + t], dot);
        }
    }

    // ---- wave reduce + sigmoid ----
#pragma unroll
    for (int off = 32; off > 0; off >>= 1) dot += __shfl_xor(dot, off, 64);
    if (lane == 0) {
        float tt = dot + W[OFF_C0];
        out[e] = 1.0f / (1.0f + expf(-tt));
    }
}

extern "C" void kernel_launch(void* const* d_in, const int* in_sizes, int n_in,
                              void* d_out, int out_size, void* d_ws, size_t ws_size,
                              hipStream_t stream) {
    const float* x    = (const float*)d_in[0];
    const int*   ei   = (const int*)d_in[1];
    const int*   te   = (const int*)d_in[2];
    const float* Wl   = (const float*)d_in[3];
    const float* bl   = (const float*)d_in[4];
    const float* Wr   = (const float*)d_in[5];
    const float* tw   = (const float*)d_in[6];
    const float* c1w  = (const float*)d_in[7];
    const float* c1b  = (const float*)d_in[8];
    const float* c2w  = (const float*)d_in[9];
    const float* c2b  = (const float*)d_in[10];
    const float* c3w  = (const float*)d_in[11];
    const float* c3b  = (const float*)d_in[12];
    const float* bn1g = (const float*)d_in[13];
    const float* bn1b = (const float*)d_in[14];
    const float* bn2g = (const float*)d_in[15];
    const float* bn2b = (const float*)d_in[16];
    const float* bn3g = (const float*)d_in[17];
    const float* bn3b = (const float*)d_in[18];
    const float* bn4g = (const float*)d_in[19];
    const float* bn4b = (const float*)d_in[20];
    const float* fc1w = (const float*)d_in[21];
    const float* fc1b = (const float*)d_in[22];
    const float* fc2w = (const float*)d_in[23];
    const float* fc2b = (const float*)d_in[24];
    float* W   = (float*)d_ws;
    int*   I   = (int*)(W + OFF_INT);
    float* out = (float*)d_out;

    hipMemsetAsync(I, 0, 2000 * sizeof(int), stream);          // cnt
    k_count<<<EG / 256, 256, 0, stream>>>(ei, I);
    k_scan<<<1, 256, 0, stream>>>(I);
    k_fill<<<EG / 256, 256, 0, stream>>>(ei, I);
    k_gather<<<500, 256, 0, stream>>>(x, I, W + OFF_MEAN);
    dim3 g2(8, 63);
    k_sage<<<g2, 256, 0, stream>>>(W + OFF_MEAN, x, Wl, bl, Wr, W + OFF_H);
    k_score<<<500, 256, 0, stream>>>(W + OFF_H, tw, W + OFF_SC);
    k_topk<<<1, 256, 0, stream>>>(W + OFF_H, tw, c1w, c1b, bn1g, bn1b, W);
    k_prep<<<12, 256, 0, stream>>>(fc1w, fc2w, bn4g, c1w, c2w, c2b, c3w, c3b,
                                   bn1g, bn2g, bn2b, bn3g, bn3b, bn4b, fc1b, fc2b, W);
    k_edges<<<ET / 4, 256, 0, stream>>>(W + OFF_H, te, W, out);
}

// Round 3
// 190.915 us; speedup vs baseline: 3.6020x; 1.1704x over previous
//
#include <hip/hip_runtime.h>
#include <hip/hip_bf16.h>
#include <math.h>

#define N_NODES 2000
#define DIN 256
#define DD 256
#define KTOP 10
#define CC 12
#define EG 64000
#define ET 50000
#define L1LEN 255
#define P1LEN 127
#define P2LEN 63
#define P3LEN 31
#define FLAT 2652
#define BN_INV 0.9999950000375f

typedef float v2 __attribute__((ext_vector_type(2)));

__device__ __forceinline__ v2 v2fma(v2 a, v2 b, v2 c) {
#if __has_builtin(__builtin_elementwise_fma)
    return __builtin_elementwise_fma(a, b, c);
#else
    v2 r; r.x = fmaf(a.x, b.x, c.x); r.y = fmaf(a.y, b.y, c.y); return r;
#endif
}
__device__ __forceinline__ v2 sp(float s) { v2 r; r.x = s; r.y = s; return r; }

// ---- workspace layout (float offsets) ----
#define OFF_MEAN   0                          // 512000
#define OFF_H      512000                     // 512000
#define OFF_SC     1024000                    // 2000 (cleared)
#define OFF_CNT    1026000                    // 2000 ints (cleared)
#define OFF_OFFS   1028000                    // 2000 ints
#define OFF_CUR    1030000                    // 2000 ints
#define OFF_NBR    1032000                    // 64000 ints
#define OFF_CONST1 1096000                    // [12][256] = 3072
#define OFF_WA     1099072                    // [t][o] 24
#define OFF_WB     1099096                    // 24
#define OFF_W2F    1099120                    // [o][t][i] 288
#define OFF_B2F    1099408                    // 12
#define OFF_W3P    1099420                    // [t][i][o] 288
#define OFF_B3F    1099708                    // 12
#define OFF_V1     1099720                    // [12][128] = 1536
#define OFF_V2     1101256                    // [12][64]  = 768
#define OFF_V3     1102024                    // [12][32]  = 384
#define OFF_C0     1102408                    // 1

// ---------------- CSR build ----------------
__global__ void k_count(const int* __restrict__ ei, int* __restrict__ I) {
    int e = blockIdx.x * 256 + threadIdx.x;
    if (e < EG) atomicAdd(&I[ei[EG + e]], 1);
}

__global__ void k_scan(int* __restrict__ I) {
    const int* cnt = I; int* offs = I + 2000; int* cur = I + 4000;
    __shared__ int part[256];
    int t = threadIdx.x;
    int base = t * 8, s = 0;
    int loc[8];
#pragma unroll
    for (int j = 0; j < 8; ++j) {
        int idx = base + j;
        int c = (idx < N_NODES) ? cnt[idx] : 0;
        loc[j] = c; s += c;
    }
    part[t] = s; __syncthreads();
    for (int d = 1; d < 256; d <<= 1) {
        int v = (t >= d) ? part[t - d] : 0;
        __syncthreads();
        part[t] += v;
        __syncthreads();
    }
    int run = part[t] - s;
#pragma unroll
    for (int j = 0; j < 8; ++j) {
        int idx = base + j;
        if (idx < N_NODES) { offs[idx] = run; cur[idx] = run; run += loc[j]; }
    }
}

__global__ void k_fill(const int* __restrict__ ei, int* __restrict__ I) {
    int e = blockIdx.x * 256 + threadIdx.x;
    if (e >= EG) return;
    int dst = ei[EG + e], src = ei[e];
    int slot = atomicAdd(&I[4000 + dst], 1);
    I[6000 + slot] = src;
}

// one wave per node: mean over neighbors
__global__ void k_gather(const float* __restrict__ x, const int* __restrict__ I,
                         float* __restrict__ mean) {
    int w = threadIdx.x >> 6, lane = threadIdx.x & 63;
    int n = blockIdx.x * 4 + w;
    const int* cnt = I; const int* offs = I + 2000; const int* nbr = I + 6000;
    int dg = cnt[n], off = offs[n];
    float4 acc = make_float4(0.f, 0.f, 0.f, 0.f);
    int j = 0;
    for (; j + 4 <= dg; j += 4) {
        int s0 = nbr[off + j], s1 = nbr[off + j + 1], s2 = nbr[off + j + 2], s3 = nbr[off + j + 3];
        float4 v0 = *(const float4*)(x + s0 * DIN + lane * 4);
        float4 v1 = *(const float4*)(x + s1 * DIN + lane * 4);
        float4 v2_ = *(const float4*)(x + s2 * DIN + lane * 4);
        float4 v3 = *(const float4*)(x + s3 * DIN + lane * 4);
        acc.x += v0.x + v1.x + v2_.x + v3.x;
        acc.y += v0.y + v1.y + v2_.y + v3.y;
        acc.z += v0.z + v1.z + v2_.z + v3.z;
        acc.w += v0.w + v1.w + v2_.w + v3.w;
    }
    for (; j < dg; ++j) {
        int s0 = nbr[off + j];
        float4 v0 = *(const float4*)(x + s0 * DIN + lane * 4);
        acc.x += v0.x; acc.y += v0.y; acc.z += v0.z; acc.w += v0.w;
    }
    float rd = 1.0f / fmaxf((float)dg, 1.0f);
    *(float4*)(mean + n * DIN + lane * 4) =
        make_float4(acc.x * rd, acc.y * rd, acc.z * rd, acc.w * rd);
}

// ---------------- h = relu(mean @ Wl^T + bl + x @ Wr^T), fused score atomics ----------------
__global__ void k_sage(const float* __restrict__ mean, const float* __restrict__ x,
                       const float* __restrict__ Wl, const float* __restrict__ bl,
                       const float* __restrict__ Wr, const float* __restrict__ tw,
                       float* __restrict__ h, float* __restrict__ sc) {
    __shared__ float As[32][33], Xs[32][33], Bls[32][33], Brs[32][33];
    int tid = threadIdx.x;
    int tx = tid & 15, ty = tid >> 4;
    int n0 = blockIdx.y * 32, d0 = blockIdx.x * 32;
    int lrow = tid >> 3, lcol = (tid & 7) * 4;
    v2 acc0 = sp(0.f), acc1 = sp(0.f);
    for (int k0 = 0; k0 < DIN; k0 += 32) {
        int gn = n0 + lrow;
        float4 av, xv;
        if (gn < N_NODES) {
            av = *(const float4*)(mean + gn * DIN + k0 + lcol);
            xv = *(const float4*)(x + gn * DIN + k0 + lcol);
        } else {
            av = make_float4(0.f, 0.f, 0.f, 0.f); xv = av;
        }
        As[lrow][lcol + 0] = av.x; As[lrow][lcol + 1] = av.y;
        As[lrow][lcol + 2] = av.z; As[lrow][lcol + 3] = av.w;
        Xs[lrow][lcol + 0] = xv.x; Xs[lrow][lcol + 1] = xv.y;
        Xs[lrow][lcol + 2] = xv.z; Xs[lrow][lcol + 3] = xv.w;
        int gd = d0 + lrow;
        float4 bv = *(const float4*)(Wl + gd * DIN + k0 + lcol);
        float4 rv = *(const float4*)(Wr + gd * DIN + k0 + lcol);
        Bls[lrow][lcol + 0] = bv.x; Bls[lrow][lcol + 1] = bv.y;
        Bls[lrow][lcol + 2] = bv.z; Bls[lrow][lcol + 3] = bv.w;
        Brs[lrow][lcol + 0] = rv.x; Brs[lrow][lcol + 1] = rv.y;
        Brs[lrow][lcol + 2] = rv.z; Brs[lrow][lcol + 3] = rv.w;
        __syncthreads();
#pragma unroll
        for (int kk = 0; kk < 32; ++kk) {
            v2 b; b.x = Bls[2 * tx][kk]; b.y = Bls[2 * tx + 1][kk];
            v2 r; r.x = Brs[2 * tx][kk]; r.y = Brs[2 * tx + 1][kk];
            acc0 = v2fma(b, sp(As[2 * ty][kk]), acc0);
            acc0 = v2fma(r, sp(Xs[2 * ty][kk]), acc0);
            acc1 = v2fma(b, sp(As[2 * ty + 1][kk]), acc1);
            acc1 = v2fma(r, sp(Xs[2 * ty + 1][kk]), acc1);
        }
        __syncthreads();
    }
    float tw0 = tw[d0 + 2 * tx], tw1 = tw[d0 + 2 * tx + 1];
    float bl0 = bl[d0 + 2 * tx], bl1 = bl[d0 + 2 * tx + 1];
    float hv[2][2];
    hv[0][0] = fmaxf(acc0.x + bl0, 0.f); hv[0][1] = fmaxf(acc0.y + bl1, 0.f);
    hv[1][0] = fmaxf(acc1.x + bl0, 0.f); hv[1][1] = fmaxf(acc1.y + bl1, 0.f);
    float s0 = fmaf(hv[0][0], tw0, hv[0][1] * tw1);
    float s1 = fmaf(hv[1][0], tw0, hv[1][1] * tw1);
#pragma unroll
    for (int i = 0; i < 2; ++i) {
        int n = n0 + 2 * ty + i;
        if (n < N_NODES) {
            h[n * DD + d0 + 2 * tx] = hv[i][0];
            h[n * DD + d0 + 2 * tx + 1] = hv[i][1];
        }
    }
#pragma unroll
    for (int off = 8; off > 0; off >>= 1) {
        s0 += __shfl_xor(s0, off, 64);
        s1 += __shfl_xor(s1, off, 64);
    }
    if (tx == 0) {
        int n = n0 + 2 * ty;
        if (n < N_NODES) atomicAdd(&sc[n], s0);
        if (n + 1 < N_NODES) atomicAdd(&sc[n + 1], s1);
    }
}

// ---------------- fused prep: v-split (blk 0-10), fold (blk 11), topk+const1 (blk 12) ----------------
__global__ void k_final(const float* __restrict__ h, const float* __restrict__ tw,
                        const float* __restrict__ c1w, const float* __restrict__ c1b,
                        const float* __restrict__ c2w, const float* __restrict__ c2b,
                        const float* __restrict__ c3w, const float* __restrict__ c3b,
                        const float* __restrict__ bn1g, const float* __restrict__ bn1b,
                        const float* __restrict__ bn2g, const float* __restrict__ bn2b,
                        const float* __restrict__ bn3g, const float* __restrict__ bn3b,
                        const float* __restrict__ bn4g, const float* __restrict__ bn4b,
                        const float* __restrict__ fc1w, const float* __restrict__ fc1b,
                        const float* __restrict__ fc2w, const float* __restrict__ fc2b,
                        float* __restrict__ W) {
    int tid = threadIdx.x;
    int blk = blockIdx.x;
    if (blk < 11) {  // v-split
        int j = blk * 256 + tid;
        if (j >= FLAT) return;
        float acc = 0.f;
        for (int k = 0; k < 128; ++k)
            acc += fc1w[k * FLAT + j] * (fc2w[k] * (BN_INV * bn4g[k]));
        int c = j / 221, pos = j - c * 221;
        if (pos < 127)      W[OFF_V1 + c * 128 + pos] = acc;
        else if (pos < 190) W[OFF_V2 + c * 64 + (pos - 127)] = acc;
        else                W[OFF_V3 + c * 32 + (pos - 190)] = acc;
        return;
    }
    if (blk == 11) {  // fold
        for (int t = tid; t < 288; t += 256) {
            int o = t / 24, r = t - o * 24, tt = r / 12, i = r - tt * 12;
            W[OFF_W2F + t] = c2w[o * 24 + i * 2 + tt] * (BN_INV * bn2g[i]);
            W[OFF_W3P + (tt * 12 + i) * 12 + o] = c3w[o * 24 + i * 2 + tt] * (BN_INV * bn3g[i]);
        }
        if (tid < 12) {
            float s2 = c2b[tid], s3 = c3b[tid];
            for (int i = 0; i < 12; ++i) {
                s2 += (c2w[tid * 24 + i * 2] + c2w[tid * 24 + i * 2 + 1]) * bn2b[i];
                s3 += (c3w[tid * 24 + i * 2] + c3w[tid * 24 + i * 2 + 1]) * bn3b[i];
            }
            W[OFF_B2F + tid] = s2;
            W[OFF_B3F + tid] = s3;
        }
        if (tid < 24) {
            int tt = tid / 12, o = tid - tt * 12;
            W[OFF_WA + tid] = c1w[o * 24 + tt] * (BN_INV * bn1g[0]);
            W[OFF_WB + tid] = c1w[o * 24 + 2 + tt] * (BN_INV * bn1g[1]);
        }
        if (tid == 0) {
            float c = fc2b[0];
            for (int k = 0; k < 128; ++k)
                c += fc2w[k] * (fc1b[k] * (BN_INV * bn4g[k]) + bn4b[k]);
            W[OFF_C0] = c;
        }
        return;
    }
    // ---- blk 12: single-wave topk, then const1 with all 256 threads ----
    __shared__ float s_tt[KTOP];
    __shared__ int   s_ti[KTOP];
    if (tid < 64) {
        int lane = tid;
        const float* sc = W + OFF_SC;
        float v[32];
#pragma unroll
        for (int s = 0; s < 32; ++s) {
            int idx = s * 64 + lane;
            v[s] = (idx < N_NODES) ? sc[idx] : -1e30f;
        }
        float p = 0.f;
#pragma unroll
        for (int k = 0; k < 4; ++k) { float t = tw[lane + 64 * k]; p = fmaf(t, t, p); }
#pragma unroll
        for (int off = 32; off > 0; off >>= 1) p += __shfl_xor(p, off, 64);
        float rnorm = 1.0f / sqrtf(p);
#pragma unroll
        for (int k = 0; k < KTOP; ++k) {
            float m = v[0];
#pragma unroll
            for (int s = 1; s < 32; ++s) m = fmaxf(m, v[s]);
#pragma unroll
            for (int off = 32; off > 0; off >>= 1) m = fmaxf(m, __shfl_xor(m, off, 64));
            int cand = 0x7fffffff;
#pragma unroll
            for (int s = 0; s < 32; ++s)
                if (v[s] == m) cand = min(cand, s * 64 + lane);
#pragma unroll
            for (int off = 32; off > 0; off >>= 1) cand = min(cand, __shfl_xor(cand, off, 64));
#pragma unroll
            for (int s = 0; s < 32; ++s)
                if (s * 64 + lane == cand) v[s] = -1e30f;
            if (lane == 0) { s_ti[k] = cand; s_tt[k] = tanhf(m * rnorm); }
        }
    }
    __syncthreads();
    float* c1c = W + OFF_CONST1;
    for (int jj = tid; jj < CC * L1LEN; jj += 256) {
        int o = jj / L1LEN, l = jj - o * L1LEN;
        float sum = c1b[o];
        sum += (c1w[o * 24 + 0] + c1w[o * 24 + 1]) * bn1b[0];
        sum += (c1w[o * 24 + 2] + c1w[o * 24 + 3]) * bn1b[1];
#pragma unroll
        for (int r = 0; r < KTOP; ++r) {
            int ch = r + 2;
            float tv = s_tt[r];
            float sr = BN_INV * bn1g[ch];
            float br = bn1b[ch];
            const float* hr = h + s_ti[r] * DD;
            float v0 = fmaf(hr[l], tv * sr, br);
            float v1 = fmaf(hr[l + 1], tv * sr, br);
            sum += c1w[o * 24 + ch * 2] * v0 + c1w[o * 24 + ch * 2 + 1] * v1;
        }
        c1c[o * 256 + l] = sum;
    }
}

// ---------------- per-edge CNN pipeline, packed-f32 math, dot fused ----------------
__launch_bounds__(256, 4)
__global__ void k_edges(const float* __restrict__ h, const int* __restrict__ te,
                        const float* __restrict__ W, float* __restrict__ out) {
    __shared__ float s1[4][CC][128];
    __shared__ float s2[4][CC][64];
    const int tid = threadIdx.x;
    const int w = tid >> 6, lane = tid & 63;
    const int e = blockIdx.x * 4 + w;

    int na = __builtin_amdgcn_readfirstlane(te[2 * e]);
    int nb = __builtin_amdgcn_readfirstlane(te[2 * e + 1]);
    const float* ha = h + na * DD;
    const float* hb = h + nb * DD;
    const float* c1c = W + OFF_CONST1;
    const float* wa = W + OFF_WA;
    const float* wb = W + OFF_WB;
    const float* w2 = W + OFF_W2F;
    const float* b2 = W + OFF_B2F;
    const float* w3p = W + OFF_W3P;
    const float* b3 = W + OFF_B3F;
    const float* V1 = W + OFF_V1;
    const float* V2 = W + OFF_V2;
    const float* V3 = W + OFF_V3;

    float dot = 0.f;

    // ---- stage 1: conv1 (decomposed) + relu + pool, packed over (u0,u1) ----
#pragma unroll
    for (int rep = 0; rep < 2; ++rep) {
        int p = lane + rep * 64;
        if (p < P1LEN) {
            float2 a01 = *(const float2*)(ha + 2 * p);
            float  a2  = ha[2 * p + 2];
            float2 b01 = *(const float2*)(hb + 2 * p);
            float  b2v = hb[2 * p + 2];
            v2 va0; va0.x = a01.x; va0.y = a01.y;   // (a0,a1)
            v2 va1; va1.x = a01.y; va1.y = a2;      // (a1,a2)
            v2 vb0; vb0.x = b01.x; vb0.y = b01.y;
            v2 vb1; vb1.x = b01.y; vb1.y = b2v;
#pragma unroll
            for (int o = 0; o < CC; ++o) {
                v2 u = *(const v2*)(c1c + o * 256 + 2 * p);
                u = v2fma(sp(wa[o]), va0, u);
                u = v2fma(sp(wa[12 + o]), va1, u);
                u = v2fma(sp(wb[o]), vb0, u);
                u = v2fma(sp(wb[12 + o]), vb1, u);
                float r = fmaxf(fmaxf(u.x, u.y), 0.0f);
                s1[w][o][p] = r;
                dot = fmaf(r, V1[o * 128 + p], dot);
            }
        }
    }
    __builtin_amdgcn_wave_barrier();

    // ---- stage 2: conv2 + relu + pool, packed over (a0,a1) ----
    if (lane < P2LEN) {
        int p = lane;
        v2 evo[CC], ovE[CC];
#pragma unroll
        for (int i = 0; i < CC; ++i) {
            float2 t2 = *(const float2*)(&s1[w][i][2 * p]);
            float e1 = s1[w][i][2 * p + 2];
            evo[i].x = t2.x; evo[i].y = t2.y;
            ovE[i].x = t2.y; ovE[i].y = e1;
        }
#pragma unroll
        for (int o = 0; o < CC; ++o) {
            v2 a = sp(b2[o]);
#pragma unroll
            for (int i = 0; i < CC; ++i) {
                a = v2fma(sp(w2[o * 24 + i]), evo[i], a);
                a = v2fma(sp(w2[o * 24 + 12 + i]), ovE[i], a);
            }
            float r = fmaxf(fmaxf(a.x, a.y), 0.0f);
            s2[w][o][p] = r;
            dot = fmaf(r, V2[o * 64 + p], dot);
        }
    }
    __builtin_amdgcn_wave_barrier();

    // ---- stage 3: conv3, packed over o-pairs, shfl pooling ----
    {
        int q = (lane < 62) ? lane : 61;
        float ve[CC], vq1[CC];
#pragma unroll
        for (int i = 0; i < CC; ++i) {
            ve[i] = s2[w][i][q];
            vq1[i] = s2[w][i][q + 1];
        }
        bool take = ((lane & 1) == 0) && (lane < 62);
        int t = lane >> 1;
#pragma unroll
        for (int op = 0; op < 6; ++op) {
            int o = 2 * op;
            v2 a; a.x = b3[o]; a.y = b3[o + 1];
#pragma unroll
            for (int i = 0; i < CC; ++i) {
                a = v2fma(sp(ve[i]), *(const v2*)(w3p + i * 12 + o), a);
                a = v2fma(sp(vq1[i]), *(const v2*)(w3p + (12 + i) * 12 + o), a);
            }
            float pnx = __shfl_xor(a.x, 1, 64);
            float pny = __shfl_xor(a.y, 1, 64);
            float r0 = fmaxf(fmaxf(a.x, pnx), 0.0f);
            float r1 = fmaxf(fmaxf(a.y, pny), 0.0f);
            if (take) {
                dot = fmaf(r0, V3[o * 32 + t], dot);
                dot = fmaf(r1, V3[(o + 1) * 32 + t], dot);
            }
        }
    }

    // ---- wave reduce + sigmoid ----
#pragma unroll
    for (int off = 32; off > 0; off >>= 1) dot += __shfl_xor(dot, off, 64);
    if (lane == 0) {
        float tt = dot + W[OFF_C0];
        out[e] = 1.0f / (1.0f + expf(-tt));
    }
}

extern "C" void kernel_launch(void* const* d_in, const int* in_sizes, int n_in,
                              void* d_out, int out_size, void* d_ws, size_t ws_size,
                              hipStream_t stream) {
    const float* x    = (const float*)d_in[0];
    const int*   ei   = (const int*)d_in[1];
    const int*   te   = (const int*)d_in[2];
    const float* Wl   = (const float*)d_in[3];
    const float* bl   = (const float*)d_in[4];
    const float* Wr   = (const float*)d_in[5];
    const float* tw   = (const float*)d_in[6];
    const float* c1w  = (const float*)d_in[7];
    const float* c1b  = (const float*)d_in[8];
    const float* c2w  = (const float*)d_in[9];
    const float* c2b  = (const float*)d_in[10];
    const float* c3w  = (const float*)d_in[11];
    const float* c3b  = (const float*)d_in[12];
    const float* bn1g = (const float*)d_in[13];
    const float* bn1b = (const float*)d_in[14];
    const float* bn2g = (const float*)d_in[15];
    const float* bn2b = (const float*)d_in[16];
    const float* bn3g = (const float*)d_in[17];
    const float* bn3b = (const float*)d_in[18];
    const float* bn4g = (const float*)d_in[19];
    const float* bn4b = (const float*)d_in[20];
    const float* fc1w = (const float*)d_in[21];
    const float* fc1b = (const float*)d_in[22];
    const float* fc2w = (const float*)d_in[23];
    const float* fc2b = (const float*)d_in[24];
    float* W   = (float*)d_ws;
    int*   I   = (int*)(W + OFF_CNT);
    float* out = (float*)d_out;

    // clear sc (2000 f32) + cnt (2000 i32) in one memset
    hipMemsetAsync(W + OFF_SC, 0, 4000 * sizeof(float), stream);
    k_count<<<EG / 256, 256, 0, stream>>>(ei, I);
    k_scan<<<1, 256, 0, stream>>>(I);
    k_fill<<<EG / 256, 256, 0, stream>>>(ei, I);
    k_gather<<<500, 256, 0, stream>>>(x, I, W + OFF_MEAN);
    dim3 g2(8, 63);
    k_sage<<<g2, 256, 0, stream>>>(W + OFF_MEAN, x, Wl, bl, Wr, tw, W + OFF_H, W + OFF_SC);
    k_final<<<13, 256, 0, stream>>>(W + OFF_H, tw, c1w, c1b, c2w, c2b, c3w, c3b,
                                    bn1g, bn1b, bn2g, bn2b, bn3g, bn3b, bn4g, bn4b,
                                    fc1w, fc1b, fc2w, fc2b, W);
    k_edges<<<ET / 4, 256, 0, stream>>>(W + OFF_H, te, W, out);
}

// Round 4
// 176.511 us; speedup vs baseline: 3.8959x; 1.0816x over previous
//
#include <hip/hip_runtime.h>
#include <hip/hip_bf16.h>
#include <math.h>

#define N_NODES 2000
#define DIN 256
#define DD 256
#define KTOP 10
#define CC 12
#define EG 64000
#define ET 50000
#define L1LEN 255
#define P1LEN 127
#define P2LEN 63
#define P3LEN 31
#define FLAT 2652
#define BN_INV 0.9999950000375f

typedef float v2 __attribute__((ext_vector_type(2)));

__device__ __forceinline__ v2 v2fma(v2 a, v2 b, v2 c) {
#if __has_builtin(__builtin_elementwise_fma)
    return __builtin_elementwise_fma(a, b, c);
#else
    v2 r; r.x = fmaf(a.x, b.x, c.x); r.y = fmaf(a.y, b.y, c.y); return r;
#endif
}
__device__ __forceinline__ v2 sp(float s) { v2 r; r.x = s; r.y = s; return r; }

// ---- workspace layout (float offsets) ----
// Tables live in the first 8K floats of the mean region: k_gather/k_sage use
// mean FIRST, then k_final overwrites the head with tables for k_edges.
#define OFF_C1V    0                          // [12][128] float4 = 6144 floats
#define OFF_WA     6144                       // [t][o] 24
#define OFF_WB     6168                       // 24
#define OFF_W2F    6192                       // [o][t][i] 288
#define OFF_B2F    6480                       // 12
#define OFF_W3P    6492                       // [t][i][o] 288
#define OFF_B3F    6780                       // 12
#define OFF_V2     6792                       // [12][64] = 768
#define OFF_V3     7560                       // [12][32] = 384
#define OFF_C0     7944                       // 1
#define OFF_MEAN   0                          // 512000 (shares head with tables, see above)
#define OFF_H      512000                     // 512000
#define OFF_SC     1024000                    // 2000 (cleared)
#define OFF_CNT    1026000                    // 2000 ints (cleared)
#define OFF_OFFS   1028000                    // 2000 ints
#define OFF_CUR    1030000                    // 2000 ints
#define OFF_NBR    1032000                    // 64000 ints

// ---------------- CSR build ----------------
__global__ void k_count(const int* __restrict__ ei, int* __restrict__ I) {
    int e = blockIdx.x * 256 + threadIdx.x;
    if (e < EG) atomicAdd(&I[ei[EG + e]], 1);
}

__global__ void k_scan(int* __restrict__ I) {
    const int* cnt = I; int* offs = I + 2000; int* cur = I + 4000;
    __shared__ int part[256];
    int t = threadIdx.x;
    int base = t * 8, s = 0;
    int loc[8];
#pragma unroll
    for (int j = 0; j < 8; ++j) {
        int idx = base + j;
        int c = (idx < N_NODES) ? cnt[idx] : 0;
        loc[j] = c; s += c;
    }
    part[t] = s; __syncthreads();
    for (int d = 1; d < 256; d <<= 1) {
        int v = (t >= d) ? part[t - d] : 0;
        __syncthreads();
        part[t] += v;
        __syncthreads();
    }
    int run = part[t] - s;
#pragma unroll
    for (int j = 0; j < 8; ++j) {
        int idx = base + j;
        if (idx < N_NODES) { offs[idx] = run; cur[idx] = run; run += loc[j]; }
    }
}

__global__ void k_fill(const int* __restrict__ ei, int* __restrict__ I) {
    int e = blockIdx.x * 256 + threadIdx.x;
    if (e >= EG) return;
    int dst = ei[EG + e], src = ei[e];
    int slot = atomicAdd(&I[4000 + dst], 1);
    I[6000 + slot] = src;
}

// one wave per node: mean over neighbors
__global__ void k_gather(const float* __restrict__ x, const int* __restrict__ I,
                         float* __restrict__ mean) {
    int w = threadIdx.x >> 6, lane = threadIdx.x & 63;
    int n = blockIdx.x * 4 + w;
    const int* cnt = I; const int* offs = I + 2000; const int* nbr = I + 6000;
    int dg = cnt[n], off = offs[n];
    float4 acc = make_float4(0.f, 0.f, 0.f, 0.f);
    int j = 0;
    for (; j + 4 <= dg; j += 4) {
        int s0 = nbr[off + j], s1 = nbr[off + j + 1], s2 = nbr[off + j + 2], s3 = nbr[off + j + 3];
        float4 v0 = *(const float4*)(x + s0 * DIN + lane * 4);
        float4 v1 = *(const float4*)(x + s1 * DIN + lane * 4);
        float4 v2_ = *(const float4*)(x + s2 * DIN + lane * 4);
        float4 v3 = *(const float4*)(x + s3 * DIN + lane * 4);
        acc.x += v0.x + v1.x + v2_.x + v3.x;
        acc.y += v0.y + v1.y + v2_.y + v3.y;
        acc.z += v0.z + v1.z + v2_.z + v3.z;
        acc.w += v0.w + v1.w + v2_.w + v3.w;
    }
    for (; j < dg; ++j) {
        int s0 = nbr[off + j];
        float4 v0 = *(const float4*)(x + s0 * DIN + lane * 4);
        acc.x += v0.x; acc.y += v0.y; acc.z += v0.z; acc.w += v0.w;
    }
    float rd = 1.0f / fmaxf((float)dg, 1.0f);
    *(float4*)(mean + n * DIN + lane * 4) =
        make_float4(acc.x * rd, acc.y * rd, acc.z * rd, acc.w * rd);
}

// ---------------- h = relu(mean @ Wl^T + bl + x @ Wr^T), fused score atomics ----------------
__global__ void k_sage(const float* __restrict__ mean, const float* __restrict__ x,
                       const float* __restrict__ Wl, const float* __restrict__ bl,
                       const float* __restrict__ Wr, const float* __restrict__ tw,
                       float* __restrict__ h, float* __restrict__ sc) {
    __shared__ float As[32][33], Xs[32][33], Bls[32][33], Brs[32][33];
    int tid = threadIdx.x;
    int tx = tid & 15, ty = tid >> 4;
    int n0 = blockIdx.y * 32, d0 = blockIdx.x * 32;
    int lrow = tid >> 3, lcol = (tid & 7) * 4;
    v2 acc0 = sp(0.f), acc1 = sp(0.f);
    for (int k0 = 0; k0 < DIN; k0 += 32) {
        int gn = n0 + lrow;
        float4 av, xv;
        if (gn < N_NODES) {
            av = *(const float4*)(mean + gn * DIN + k0 + lcol);
            xv = *(const float4*)(x + gn * DIN + k0 + lcol);
        } else {
            av = make_float4(0.f, 0.f, 0.f, 0.f); xv = av;
        }
        As[lrow][lcol + 0] = av.x; As[lrow][lcol + 1] = av.y;
        As[lrow][lcol + 2] = av.z; As[lrow][lcol + 3] = av.w;
        Xs[lrow][lcol + 0] = xv.x; Xs[lrow][lcol + 1] = xv.y;
        Xs[lrow][lcol + 2] = xv.z; Xs[lrow][lcol + 3] = xv.w;
        int gd = d0 + lrow;
        float4 bv = *(const float4*)(Wl + gd * DIN + k0 + lcol);
        float4 rv = *(const float4*)(Wr + gd * DIN + k0 + lcol);
        Bls[lrow][lcol + 0] = bv.x; Bls[lrow][lcol + 1] = bv.y;
        Bls[lrow][lcol + 2] = bv.z; Bls[lrow][lcol + 3] = bv.w;
        Brs[lrow][lcol + 0] = rv.x; Brs[lrow][lcol + 1] = rv.y;
        Brs[lrow][lcol + 2] = rv.z; Brs[lrow][lcol + 3] = rv.w;
        __syncthreads();
#pragma unroll
        for (int kk = 0; kk < 32; ++kk) {
            v2 b; b.x = Bls[2 * tx][kk]; b.y = Bls[2 * tx + 1][kk];
            v2 r; r.x = Brs[2 * tx][kk]; r.y = Brs[2 * tx + 1][kk];
            acc0 = v2fma(b, sp(As[2 * ty][kk]), acc0);
            acc0 = v2fma(r, sp(Xs[2 * ty][kk]), acc0);
            acc1 = v2fma(b, sp(As[2 * ty + 1][kk]), acc1);
            acc1 = v2fma(r, sp(Xs[2 * ty + 1][kk]), acc1);
        }
        __syncthreads();
    }
    float tw0 = tw[d0 + 2 * tx], tw1 = tw[d0 + 2 * tx + 1];
    float bl0 = bl[d0 + 2 * tx], bl1 = bl[d0 + 2 * tx + 1];
    float hv[2][2];
    hv[0][0] = fmaxf(acc0.x + bl0, 0.f); hv[0][1] = fmaxf(acc0.y + bl1, 0.f);
    hv[1][0] = fmaxf(acc1.x + bl0, 0.f); hv[1][1] = fmaxf(acc1.y + bl1, 0.f);
    float s0 = fmaf(hv[0][0], tw0, hv[0][1] * tw1);
    float s1 = fmaf(hv[1][0], tw0, hv[1][1] * tw1);
#pragma unroll
    for (int i = 0; i < 2; ++i) {
        int n = n0 + 2 * ty + i;
        if (n < N_NODES) {
            h[n * DD + d0 + 2 * tx] = hv[i][0];
            h[n * DD + d0 + 2 * tx + 1] = hv[i][1];
        }
    }
#pragma unroll
    for (int off = 8; off > 0; off >>= 1) {
        s0 += __shfl_xor(s0, off, 64);
        s1 += __shfl_xor(s1, off, 64);
    }
    if (tx == 0) {
        int n = n0 + 2 * ty;
        if (n < N_NODES) atomicAdd(&sc[n], s0);
        if (n + 1 < N_NODES) atomicAdd(&sc[n + 1], s1);
    }
}

// ---------------- fused prep: v-split (blk 0-10), fold (blk 11), topk+const1 (blk 12) ----------------
__global__ void k_final(const float* __restrict__ h, const float* __restrict__ tw,
                        const float* __restrict__ c1w, const float* __restrict__ c1b,
                        const float* __restrict__ c2w, const float* __restrict__ c2b,
                        const float* __restrict__ c3w, const float* __restrict__ c3b,
                        const float* __restrict__ bn1g, const float* __restrict__ bn1b,
                        const float* __restrict__ bn2g, const float* __restrict__ bn2b,
                        const float* __restrict__ bn3g, const float* __restrict__ bn3b,
                        const float* __restrict__ bn4g, const float* __restrict__ bn4b,
                        const float* __restrict__ fc1w, const float* __restrict__ fc1b,
                        const float* __restrict__ fc2w, const float* __restrict__ fc2b,
                        float* __restrict__ W) {
    int tid = threadIdx.x;
    int blk = blockIdx.x;
    if (blk < 11) {  // v-split
        int j = blk * 256 + tid;
        if (j >= FLAT) return;
        float acc = 0.f;
        for (int k = 0; k < 128; ++k)
            acc += fc1w[k * FLAT + j] * (fc2w[k] * (BN_INV * bn4g[k]));
        int c = j / 221, pos = j - c * 221;
        if (pos < 127)      W[OFF_C1V + (c * 128 + pos) * 4 + 2] = acc;   // C1V .z
        else if (pos < 190) W[OFF_V2 + c * 64 + (pos - 127)] = acc;
        else                W[OFF_V3 + c * 32 + (pos - 190)] = acc;
        return;
    }
    if (blk == 11) {  // fold
        for (int t = tid; t < 288; t += 256) {
            int o = t / 24, r = t - o * 24, tt = r / 12, i = r - tt * 12;
            W[OFF_W2F + t] = c2w[o * 24 + i * 2 + tt] * (BN_INV * bn2g[i]);
            W[OFF_W3P + (tt * 12 + i) * 12 + o] = c3w[o * 24 + i * 2 + tt] * (BN_INV * bn3g[i]);
        }
        if (tid < 12) {
            float s2 = c2b[tid], s3 = c3b[tid];
            for (int i = 0; i < 12; ++i) {
                s2 += (c2w[tid * 24 + i * 2] + c2w[tid * 24 + i * 2 + 1]) * bn2b[i];
                s3 += (c3w[tid * 24 + i * 2] + c3w[tid * 24 + i * 2 + 1]) * bn3b[i];
            }
            W[OFF_B2F + tid] = s2;
            W[OFF_B3F + tid] = s3;
        }
        if (tid < 24) {
            int tt = tid / 12, o = tid - tt * 12;
            W[OFF_WA + tid] = c1w[o * 24 + tt] * (BN_INV * bn1g[0]);
            W[OFF_WB + tid] = c1w[o * 24 + 2 + tt] * (BN_INV * bn1g[1]);
        }
        if (tid == 0) {
            float c = fc2b[0];
            for (int k = 0; k < 128; ++k)
                c += fc2w[k] * (fc1b[k] * (BN_INV * bn4g[k]) + bn4b[k]);
            W[OFF_C0] = c;
        }
        return;
    }
    // ---- blk 12: single-wave topk, then const1 (into C1V .x/.y) ----
    __shared__ float s_tt[KTOP];
    __shared__ int   s_ti[KTOP];
    if (tid < 64) {
        int lane = tid;
        const float* sc = W + OFF_SC;
        float v[32];
#pragma unroll
        for (int s = 0; s < 32; ++s) {
            int idx = s * 64 + lane;
            v[s] = (idx < N_NODES) ? sc[idx] : -1e30f;
        }
        float p = 0.f;
#pragma unroll
        for (int k = 0; k < 4; ++k) { float t = tw[lane + 64 * k]; p = fmaf(t, t, p); }
#pragma unroll
        for (int off = 32; off > 0; off >>= 1) p += __shfl_xor(p, off, 64);
        float rnorm = 1.0f / sqrtf(p);
#pragma unroll
        for (int k = 0; k < KTOP; ++k) {
            float m = v[0];
#pragma unroll
            for (int s = 1; s < 32; ++s) m = fmaxf(m, v[s]);
#pragma unroll
            for (int off = 32; off > 0; off >>= 1) m = fmaxf(m, __shfl_xor(m, off, 64));
            int cand = 0x7fffffff;
#pragma unroll
            for (int s = 0; s < 32; ++s)
                if (v[s] == m) cand = min(cand, s * 64 + lane);
#pragma unroll
            for (int off = 32; off > 0; off >>= 1) cand = min(cand, __shfl_xor(cand, off, 64));
#pragma unroll
            for (int s = 0; s < 32; ++s)
                if (s * 64 + lane == cand) v[s] = -1e30f;
            if (lane == 0) { s_ti[k] = cand; s_tt[k] = tanhf(m * rnorm); }
        }
    }
    __syncthreads();
    for (int jj = tid; jj < CC * L1LEN; jj += 256) {
        int o = jj / L1LEN, l = jj - o * L1LEN;
        float sum = c1b[o];
        sum += (c1w[o * 24 + 0] + c1w[o * 24 + 1]) * bn1b[0];
        sum += (c1w[o * 24 + 2] + c1w[o * 24 + 3]) * bn1b[1];
#pragma unroll
        for (int r = 0; r < KTOP; ++r) {
            int ch = r + 2;
            float tv = s_tt[r];
            float sr = BN_INV * bn1g[ch];
            float br = bn1b[ch];
            const float* hr = h + s_ti[r] * DD;
            float v0 = fmaf(hr[l], tv * sr, br);
            float v1 = fmaf(hr[l + 1], tv * sr, br);
            sum += c1w[o * 24 + ch * 2] * v0 + c1w[o * 24 + ch * 2 + 1] * v1;
        }
        W[OFF_C1V + (o * 128 + (l >> 1)) * 4 + (l & 1)] = sum;  // C1V .x / .y
    }
}

// ---------------- per-edge CNN pipeline: s1 in LDS, s2 in registers ----------------
__launch_bounds__(256, 6)
__global__ void k_edges(const float* __restrict__ h, const int* __restrict__ te,
                        const float* __restrict__ W, float* __restrict__ out) {
    __shared__ float s1[4][CC][128];
    const int tid = threadIdx.x;
    const int w = tid >> 6, lane = tid & 63;
    const int e = blockIdx.x * 4 + w;

    int na = __builtin_amdgcn_readfirstlane(te[2 * e]);
    int nb = __builtin_amdgcn_readfirstlane(te[2 * e + 1]);
    const float* ha = h + na * DD;
    const float* hb = h + nb * DD;
    const float4* c1v = (const float4*)(W + OFF_C1V);
    const float* wa = W + OFF_WA;
    const float* wb = W + OFF_WB;
    const float* w2 = W + OFF_W2F;
    const float* b2 = W + OFF_B2F;
    const float* w3p = W + OFF_W3P;
    const float* b3 = W + OFF_B3F;
    const float* V2 = W + OFF_V2;
    const float* V3 = W + OFF_V3;

    float dot0 = 0.f, dot1 = 0.f;

    // ---- stage 1: conv1 (decomposed) + relu + pool; fused C1V table ----
#pragma unroll
    for (int rep = 0; rep < 2; ++rep) {
        int p = lane + rep * 64;
        if (p < P1LEN) {
            float2 a01 = *(const float2*)(ha + 2 * p);
            float  a2  = ha[2 * p + 2];
            float2 b01 = *(const float2*)(hb + 2 * p);
            float  b2v = hb[2 * p + 2];
            v2 va0; va0.x = a01.x; va0.y = a01.y;
            v2 va1; va1.x = a01.y; va1.y = a2;
            v2 vb0; vb0.x = b01.x; vb0.y = b01.y;
            v2 vb1; vb1.x = b01.y; vb1.y = b2v;
#pragma unroll
            for (int o = 0; o < CC; ++o) {
                float4 cv = c1v[o * 128 + p];
                v2 u; u.x = cv.x; u.y = cv.y;
                u = v2fma(sp(wa[o]), va0, u);
                u = v2fma(sp(wa[12 + o]), va1, u);
                u = v2fma(sp(wb[o]), vb0, u);
                u = v2fma(sp(wb[12 + o]), vb1, u);
                float r = fmaxf(fmaxf(u.x, u.y), 0.0f);
                s1[w][o][p] = r;
                if (o & 1) dot1 = fmaf(r, cv.z, dot1);
                else       dot0 = fmaf(r, cv.z, dot0);
            }
        }
    }
    __builtin_amdgcn_wave_barrier();

    // ---- stage 2: conv2 + relu + pool -> registers r2[12] ----
    float r2[CC];
#pragma unroll
    for (int i = 0; i < CC; ++i) r2[i] = 0.f;
    if (lane < P2LEN) {
        int p = lane;
        v2 evo[CC], ovE[CC];
#pragma unroll
        for (int i = 0; i < CC; ++i) {
            float2 t2 = *(const float2*)(&s1[w][i][2 * p]);
            float e1 = s1[w][i][2 * p + 2];
            evo[i].x = t2.x; evo[i].y = t2.y;
            ovE[i].x = t2.y; ovE[i].y = e1;
        }
#pragma unroll
        for (int o = 0; o < CC; ++o) {
            v2 a = sp(b2[o]);
#pragma unroll
            for (int i = 0; i < CC; ++i) {
                a = v2fma(sp(w2[o * 24 + i]), evo[i], a);
                a = v2fma(sp(w2[o * 24 + 12 + i]), ovE[i], a);
            }
            float r = fmaxf(fmaxf(a.x, a.y), 0.0f);
            r2[o] = r;
            if (o & 1) dot1 = fmaf(r, V2[o * 64 + p], dot1);
            else       dot0 = fmaf(r, V2[o * 64 + p], dot0);
        }
    }

    // ---- stage 3: conv3 from registers; neighbor via shfl_down ----
    {
        float vq1[CC];
#pragma unroll
        for (int i = 0; i < CC; ++i) vq1[i] = __shfl_down(r2[i], 1, 64);
        bool take = ((lane & 1) == 0) && (lane < 62);
        int t = lane >> 1;
#pragma unroll
        for (int op = 0; op < 6; ++op) {
            int o = 2 * op;
            v2 a; a.x = b3[o]; a.y = b3[o + 1];
#pragma unroll
            for (int i = 0; i < CC; ++i) {
                a = v2fma(sp(r2[i]), *(const v2*)(w3p + i * 12 + o), a);
                a = v2fma(sp(vq1[i]), *(const v2*)(w3p + (12 + i) * 12 + o), a);
            }
            float pnx = __shfl_xor(a.x, 1, 64);
            float pny = __shfl_xor(a.y, 1, 64);
            float r0 = fmaxf(fmaxf(a.x, pnx), 0.0f);
            float r1 = fmaxf(fmaxf(a.y, pny), 0.0f);
            if (take) {
                dot0 = fmaf(r0, V3[o * 32 + t], dot0);
                dot1 = fmaf(r1, V3[(o + 1) * 32 + t], dot1);
            }
        }
    }

    // ---- wave reduce + sigmoid ----
    float dot = dot0 + dot1;
#pragma unroll
    for (int off = 32; off > 0; off >>= 1) dot += __shfl_xor(dot, off, 64);
    if (lane == 0) {
        float tt = dot + W[OFF_C0];
        out[e] = 1.0f / (1.0f + expf(-tt));
    }
}

extern "C" void kernel_launch(void* const* d_in, const int* in_sizes, int n_in,
                              void* d_out, int out_size, void* d_ws, size_t ws_size,
                              hipStream_t stream) {
    const float* x    = (const float*)d_in[0];
    const int*   ei   = (const int*)d_in[1];
    const int*   te   = (const int*)d_in[2];
    const float* Wl   = (const float*)d_in[3];
    const float* bl   = (const float*)d_in[4];
    const float* Wr   = (const float*)d_in[5];
    const float* tw   = (const float*)d_in[6];
    const float* c1w  = (const float*)d_in[7];
    const float* c1b  = (const float*)d_in[8];
    const float* c2w  = (const float*)d_in[9];
    const float* c2b  = (const float*)d_in[10];
    const float* c3w  = (const float*)d_in[11];
    const float* c3b  = (const float*)d_in[12];
    const float* bn1g = (const float*)d_in[13];
    const float* bn1b = (const float*)d_in[14];
    const float* bn2g = (const float*)d_in[15];
    const float* bn2b = (const float*)d_in[16];
    const float* bn3g = (const float*)d_in[17];
    const float* bn3b = (const float*)d_in[18];
    const float* bn4g = (const float*)d_in[19];
    const float* bn4b = (const float*)d_in[20];
    const float* fc1w = (const float*)d_in[21];
    const float* fc1b = (const float*)d_in[22];
    const float* fc2w = (const float*)d_in[23];
    const float* fc2b = (const float*)d_in[24];
    float* W   = (float*)d_ws;
    int*   I   = (int*)(W + OFF_CNT);
    float* out = (float*)d_out;

    // clear sc (2000 f32) + cnt (2000 i32) in one memset
    hipMemsetAsync(W + OFF_SC, 0, 4000 * sizeof(float), stream);
    k_count<<<EG / 256, 256, 0, stream>>>(ei, I);
    k_scan<<<1, 256, 0, stream>>>(I);
    k_fill<<<EG / 256, 256, 0, stream>>>(ei, I);
    k_gather<<<500, 256, 0, stream>>>(x, I, W + OFF_MEAN);
    dim3 g2(8, 63);
    k_sage<<<g2, 256, 0, stream>>>(W + OFF_MEAN, x, Wl, bl, Wr, tw, W + OFF_H, W + OFF_SC);
    k_final<<<13, 256, 0, stream>>>(W + OFF_H, tw, c1w, c1b, c2w, c2b, c3w, c3b,
                                    bn1g, bn1b, bn2g, bn2b, bn3g, bn3b, bn4g, bn4b,
                                    fc1w, fc1b, fc2w, fc2b, W);
    k_edges<<<ET / 4, 256, 0, stream>>>(W + OFF_H, te, W, out);
}